// Round 22
// baseline (171.418 us; speedup 1.0000x reference)
//
#include <hip/hip_runtime.h>
#include <cstddef>

// ---------------------------------------------------------------------------
// GraphFiLM: 2x FiLMConv(mean agg) + leaky_relu + linear head.
// Round 21: gemm W staging -> single-mat double-buffered (2x8KB WT, prefetch
// mat m+1 under mat m's MFMAs; 24KB LDS total) + __launch_bounds__(256,6)
// VGPR cap -> 6 blocks/CU (was 5). Rest unchanged from R20.
// ---------------------------------------------------------------------------

#define THREADS 256
#define NB 512
#define NPSHIFT 9
#define NPSZ 512
#define CAP 10240

typedef unsigned short u16;
typedef unsigned char u8;
typedef unsigned int u32;
typedef short bf16x8 __attribute__((ext_vector_type(8)));
typedef float f32x4 __attribute__((ext_vector_type(4)));
typedef float f32x2 __attribute__((ext_vector_type(2)));

__device__ __forceinline__ u16 f2b(float f) {
  u32 u = __float_as_uint(f);
  u32 r = (u + 0x7FFFu + ((u >> 16) & 1u)) >> 16;
  return (u16)r;
}
__device__ __forceinline__ float b2f(u16 u) {
  return __uint_as_float(((u32)u) << 16);
}
__device__ __forceinline__ u8 f2fp8(float v) {
  return (u8)(__builtin_amdgcn_cvt_pk_fp8_f32(v, v, 0, false) & 0xFF);
}

// ---------------- weight prep + two-pass bucket scatter (merged) ----------
struct WSrc {
  const float* p;
  int ld;
  int off;
};
struct WPack {
  WSrc m[12];
};

__global__ __launch_bounds__(THREADS) void prep_and_scatter(
    WPack wp, u16* __restrict__ Wp, const int* __restrict__ src,
    const int* __restrict__ dst, int* __restrict__ gcur, u32* __restrict__ buck,
    int E, int CH, int P) {
  int b = blockIdx.x, t = threadIdx.x;
  if (b < 12) {
    WSrc ws = wp.m[b];
    u16* dstp = Wp + b * 4096;
#pragma unroll
    for (int i = 0; i < 16; ++i) {
      int e = t + 256 * i;
      int n = e >> 6, k = e & 63;
      float v = ws.p[(size_t)k * ws.ld + ws.off + n];
      dstp[e ^ ((n & 7) << 3)] = f2b(v);
    }
    return;
  }
  __shared__ int h[256];
  __shared__ int cur[256];
  int hb = b - 12;
  h[t] = 0;
  __syncthreads();
  int lo = hb * CH;
  int hi = min(lo + CH, E);
  if (lo >= E) return;
  for (int i = lo + t; i < hi; i += THREADS) atomicAdd(&h[dst[i] >> NPSHIFT], 1);
  __syncthreads();
  if (t < P) {
    int base = h[t] ? atomicAdd(&gcur[t], h[t]) : 0;
    cur[t] = t * CAP + base;
  }
  __syncthreads();
  for (int i = lo + t; i < hi; i += THREADS) {
    int d = dst[i];
    int pos = atomicAdd(&cur[d >> NPSHIFT], 1);
    buck[pos] = (u32)src[i] | ((u32)(d & (NPSZ - 1)) << 17);
  }
}

// ---------------- gemm body: single-mat double-buffered W (24KB LDS) ------
// mats 0..2 (trio0): skip -> S (bf16); mats 3..5 (trio1): film -> H(fp8),
// BETA, GAMMA. WT = two 4096-u16 buffers; prefetch mat m+1 under mat m.
template <int INBF16>
__device__ __forceinline__ void gemm_body(
    u16* XT, u16* WT, int row0, const void* __restrict__ Xv, int N,
    const u16* __restrict__ WpL, const float* __restrict__ bfilm,
    u8* __restrict__ H8, u16* __restrict__ BETA, u16* __restrict__ GAMMA,
    u16* __restrict__ S) {
  int t = threadIdx.x;
  {
    int row = t >> 2, kq = (t & 3) * 16;
    int gr = row0 + row;
    uint4 w0 = {0, 0, 0, 0}, w1 = {0, 0, 0, 0};
    if (gr < N) {
      if (INBF16) {
        const uint4* xp = (const uint4*)((const u16*)Xv + (size_t)gr * 64 + kq);
        w0 = xp[0];
        w1 = xp[1];
      } else {
        const float* xp = (const float*)Xv + (size_t)gr * 64 + kq;
        float4 f0 = ((const float4*)xp)[0];
        float4 f1 = ((const float4*)xp)[1];
        float4 f2 = ((const float4*)xp)[2];
        float4 f3 = ((const float4*)xp)[3];
        w0.x = f2b(f0.x) | ((u32)f2b(f0.y) << 16);
        w0.y = f2b(f0.z) | ((u32)f2b(f0.w) << 16);
        w0.z = f2b(f1.x) | ((u32)f2b(f1.y) << 16);
        w0.w = f2b(f1.z) | ((u32)f2b(f1.w) << 16);
        w1.x = f2b(f2.x) | ((u32)f2b(f2.y) << 16);
        w1.y = f2b(f2.z) | ((u32)f2b(f2.w) << 16);
        w1.z = f2b(f3.x) | ((u32)f2b(f3.y) << 16);
        w1.w = f2b(f3.z) | ((u32)f2b(f3.w) << 16);
      }
    }
    int e = row * 64 + kq;
    int s = (row & 7) << 3;
    *(uint4*)&XT[e ^ s] = w0;
    *(uint4*)&XT[(e + 8) ^ s] = w1;
  }
  const uint4* wsrc = (const uint4*)WpL;
  // stage mat 0 into buffer 0 (512 uint4 = 8KB)
  {
    uint4* wdst = (uint4*)WT;
    for (int i = t; i < 512; i += THREADS) wdst[i] = wsrc[i];
  }
  __syncthreads();  // X + mat0 ready

  int lane = t & 63, wid = t >> 6;
  int arow = wid * 16 + (lane & 15);
  int kb = (lane >> 4) << 3;
  int as = (arow & 7) << 3;
  bf16x8 A0 = *(const bf16x8*)&XT[(arow * 64 + kb) ^ as];
  bf16x8 A1 = *(const bf16x8*)&XT[(arow * 64 + 32 + kb) ^ as];

  const f32x4 z = {0.f, 0.f, 0.f, 0.f};
  int rbase = wid * 16 + ((lane >> 4) << 2);
  int cbase = lane & 15;

  f32x4 acc[3][4];

#pragma unroll
  for (int m = 0; m < 6; ++m) {
    // prefetch mat m+1 into the other buffer (WAR vs mat m-1 reads is
    // protected by the barrier at the end of the previous iteration)
    if (m < 5) {
      uint4* wdst = (uint4*)(WT + ((m + 1) & 1) * 4096);
      for (int i = t; i < 512; i += THREADS) wdst[i] = wsrc[(m + 1) * 512 + i];
    }
    int a = m % 3;
    const u16* wb = WT + (m & 1) * 4096;
#pragma unroll
    for (int ct = 0; ct < 4; ++ct) {
      int n = ct * 16 + cbase;
      int sw = (n & 7) << 3;
      bf16x8 B0 = *(const bf16x8*)&wb[(n * 64 + kb) ^ sw];
      bf16x8 B1 = *(const bf16x8*)&wb[(n * 64 + 32 + kb) ^ sw];
      f32x4 v = z;
      v = __builtin_amdgcn_mfma_f32_16x16x32_bf16(A0, B0, v, 0, 0, 0);
      v = __builtin_amdgcn_mfma_f32_16x16x32_bf16(A1, B1, v, 0, 0, 0);
      acc[a][ct] = v;
    }
    if (m == 2) {
      // trio0 epilogue: S = relu(fsg * skip + fsb)
#pragma unroll
      for (int ct = 0; ct < 4; ++ct) {
        int c = ct * 16 + cbase;
#pragma unroll
        for (int r = 0; r < 4; ++r) {
          int gr = row0 + rbase + r;
          if (gr < N) {
            float v = fmaxf(fmaf(acc[2][ct][r], acc[0][ct][r], acc[1][ct][r]), 0.f);
            S[(size_t)gr * 64 + c] = f2b(v);
          }
        }
      }
    }
    if (m == 5) {
      // trio1 epilogue: H (fp8), BETA, GAMMA
#pragma unroll
      for (int ct = 0; ct < 4; ++ct) {
        int c = ct * 16 + cbase;
        float bb = bfilm[c];
        float bg = bfilm[64 + c];
#pragma unroll
        for (int r = 0; r < 4; ++r) {
          int gr = row0 + rbase + r;
          if (gr < N) {
            size_t o = (size_t)gr * 64 + c;
            H8[o] = f2fp8(acc[0][ct][r]);
            BETA[o] = f2b(acc[1][ct][r] + bb);
            GAMMA[o] = f2b(acc[2][ct][r] + bg);
          }
        }
      }
    }
    __syncthreads();  // mat m reads done; mat m+1 staged
  }
}

// ---------------- csr body ----------------
__device__ __forceinline__ void csr_body(
    char* smem, int p, const u32* __restrict__ buck, const int* __restrict__ gcur,
    int* __restrict__ begA, int* __restrict__ degA, int* __restrict__ csr,
    int* __restrict__ perm, int N, int P) {
  int* hA = (int*)smem;
  int* hB = hA + NPSZ;
  int* cur = hB + NPSZ;
  int* h64 = cur + NPSZ;
  int* c64 = h64 + 64;
  int t = threadIdx.x;
  int cnt = gcur[p];
  int pbase = p * CAP;
  hA[t] = 0;
  hA[t + 256] = 0;
  __syncthreads();
  for (int i = t; i < cnt; i += THREADS) atomicAdd(&hA[buck[pbase + i] >> 17], 1);
  __syncthreads();
  int deg0 = hA[t], deg1 = hA[t + 256];
  int* s = hA;
  int* d2 = hB;
  for (int off = 1; off < NPSZ; off <<= 1) {
#pragma unroll
    for (int r = 0; r < 2; ++r) {
      int idx = t + r * 256;
      int v = s[idx];
      if (idx >= off) v += s[idx - off];
      d2[idx] = v;
    }
    __syncthreads();
    int* tmp = s;
    s = d2;
    d2 = tmp;
  }
#pragma unroll
  for (int r = 0; r < 2; ++r) {
    int idx = t + r * 256;
    int excl = idx ? s[idx - 1] : 0;
    cur[idx] = excl;
    int node = (p << NPSHIFT) + idx;
    if (node < N) {
      begA[node] = pbase + excl;
      degA[node] = s[idx] - excl;
    }
  }
  __syncthreads();
  for (int i = t; i < cnt; i += THREADS) {
    u32 w = buck[pbase + i];
    int pos = atomicAdd(&cur[w >> 17], 1);
    csr[pbase + pos] = (int)(w & 0x1FFFFu);
  }
  {
    int padend = min(cnt + 160, CAP);
    for (int i = cnt + t; i < padend; i += THREADS) csr[pbase + i] = 0;
  }
  __syncthreads();
  if (t < 64) h64[t] = 0;
  __syncthreads();
  int b0 = min(deg0, 63), b1 = min(deg1, 63);
  atomicAdd(&h64[b0], 1);
  atomicAdd(&h64[b1], 1);
  __syncthreads();
  if (t == 0) {
    int run = 0;
    for (int i = 0; i < 64; ++i) {
      int v = h64[i];
      c64[i] = run;
      run += v;
    }
  }
  __syncthreads();
  int base_out = p << NPSHIFT;
  int pos0 = atomicAdd(&c64[b0], 1);
  perm[base_out + pos0] = base_out + t;
  int pos1 = atomicAdd(&c64[b1], 1);
  perm[base_out + pos1] = base_out + t + 256;
}

// ---------------- fused: build_csr (blocks 0..P-1) + gemm layer-1 ----------
__global__ __launch_bounds__(THREADS, 6) void build_and_gemm0(
    const u32* __restrict__ buck, const int* __restrict__ gcur,
    int* __restrict__ begA, int* __restrict__ degA, int* __restrict__ csr,
    int* __restrict__ perm, const float* __restrict__ X, int N,
    const u16* __restrict__ Wp, const float* __restrict__ bfilm,
    u8* __restrict__ H8, u16* __restrict__ BETA, u16* __restrict__ GAMMA,
    u16* __restrict__ S, int P) {
  __shared__ __align__(16) char smem[24576];  // gemm: 8K XT + 16K WT; csr: 6.5K
  if ((int)blockIdx.x < P) {
    csr_body(smem, blockIdx.x, buck, gcur, begA, degA, csr, perm, N, P);
  } else {
    u16* XT = (u16*)smem;
    u16* WT = XT + 4096;
    int row0 = ((int)blockIdx.x - P) * 64;
    gemm_body<0>(XT, WT, row0, X, N, Wp, bfilm, H8, BETA, GAMMA, S);
  }
}

// ---------------- standalone gemm (layer 2, bf16 input) ----------
__global__ __launch_bounds__(THREADS, 6) void gemm_l2(
    const u16* __restrict__ X2, int N, const u16* __restrict__ WpL,
    const float* __restrict__ bfilm, u8* __restrict__ H8, u16* __restrict__ BETA,
    u16* __restrict__ GAMMA, u16* __restrict__ S) {
  __shared__ __align__(16) char smem[24576];
  u16* XT = (u16*)smem;
  u16* WT = XT + 4096;
  gemm_body<1>(XT, WT, blockIdx.x * 64, X2, N, WpL, bfilm, H8, BETA, GAMMA, S);
}

// ---------------- dst-centric aggregation v9 (fp8 H gather) ----------------
template <int FINAL>
__global__ __launch_bounds__(THREADS) void agg_kernel(
    const u8* __restrict__ H8, const u16* __restrict__ GAMMA,
    const u16* __restrict__ BETA, const u16* __restrict__ S,
    const int* __restrict__ begA, const int* __restrict__ degA,
    const int* __restrict__ csr, const int* __restrict__ perm,
    u16* __restrict__ Xn, const float* __restrict__ Wout,
    const float* __restrict__ bout, float* __restrict__ out, int N, int PCAP) {
  int wid = blockIdx.x * 4 + (threadIdx.x >> 6);
  int lane = threadIdx.x & 63;
  int q = lane >> 4;
  int fl = lane & 15;
  int node = perm[wid * 4 + q];
  bool valid = node < N;
  int nd = valid ? node : N - 1;
  int beg = begA[nd];
  int deg = valid ? degA[nd] : 0;
  int m = deg;
  m = max(m, __shfl_xor(m, 16, 64));
  m = max(m, __shfl_xor(m, 32, 64));

  size_t nb4 = (size_t)nd * 16 + fl;
  const uint2* G2 = (const uint2*)GAMMA;
  const uint2* B2 = (const uint2*)BETA;
  const u32* H1 = (const u32*)H8;
  const uint2* S2 = (const uint2*)S;
  uint2 gp = G2[nb4];
  uint2 bp = B2[nb4];

  auto unpA = [](u32 h) -> f32x2 {
    f32x2 r = {__uint_as_float(h << 16), __uint_as_float(h & 0xFFFF0000u)};
    return r;
  };
  f32x2 gA = unpA(gp.x), gB = unpA(gp.y);
  f32x2 bA = unpA(bp.x), bB = unpA(bp.y);
  const f32x2 zz = {0.f, 0.f};
  f32x2 accA = zz, accB = zz;
  int qb = q * 16;

  for (int c = 0; c < m; c += 16) {        // uniform
    int li = beg + c + fl;
    int idxv = csr[min(li, PCAP - 1)];     // clamped; slack padded with 0
    int nin = min(16, m - c);              // uniform
#pragma unroll 4
    for (int u = 0; u < 16; u += 4) {
      if (u >= nin) break;                 // uniform condition
      int s0 = __shfl(idxv, qb + u + 0, 64);
      int s1 = __shfl(idxv, qb + u + 1, 64);
      int s2 = __shfl(idxv, qb + u + 2, 64);
      int s3 = __shfl(idxv, qb + u + 3, 64);
      u32 h0 = H1[(size_t)s0 * 16 + fl];
      u32 h1 = H1[(size_t)s1 * 16 + fl];
      u32 h2 = H1[(size_t)s2 * 16 + fl];
      u32 h3 = H1[(size_t)s3 * 16 + fl];
      int e0 = c + u;
      f32x2 lo, hi, mA, mB;
      bool ok;
      lo = __builtin_amdgcn_cvt_pk_f32_fp8((int)h0, false);
      hi = __builtin_amdgcn_cvt_pk_f32_fp8((int)h0, true);
      mA = __builtin_elementwise_max(__builtin_elementwise_fma(gA, lo, bA), zz);
      mB = __builtin_elementwise_max(__builtin_elementwise_fma(gB, hi, bB), zz);
      ok = e0 + 0 < deg;
      accA += ok ? mA : zz;
      accB += ok ? mB : zz;
      lo = __builtin_amdgcn_cvt_pk_f32_fp8((int)h1, false);
      hi = __builtin_amdgcn_cvt_pk_f32_fp8((int)h1, true);
      mA = __builtin_elementwise_max(__builtin_elementwise_fma(gA, lo, bA), zz);
      mB = __builtin_elementwise_max(__builtin_elementwise_fma(gB, hi, bB), zz);
      ok = e0 + 1 < deg;
      accA += ok ? mA : zz;
      accB += ok ? mB : zz;
      lo = __builtin_amdgcn_cvt_pk_f32_fp8((int)h2, false);
      hi = __builtin_amdgcn_cvt_pk_f32_fp8((int)h2, true);
      mA = __builtin_elementwise_max(__builtin_elementwise_fma(gA, lo, bA), zz);
      mB = __builtin_elementwise_max(__builtin_elementwise_fma(gB, hi, bB), zz);
      ok = e0 + 2 < deg;
      accA += ok ? mA : zz;
      accB += ok ? mB : zz;
      lo = __builtin_amdgcn_cvt_pk_f32_fp8((int)h3, false);
      hi = __builtin_amdgcn_cvt_pk_f32_fp8((int)h3, true);
      mA = __builtin_elementwise_max(__builtin_elementwise_fma(gA, lo, bA), zz);
      mB = __builtin_elementwise_max(__builtin_elementwise_fma(gB, hi, bB), zz);
      ok = e0 + 3 < deg;
      accA += ok ? mA : zz;
      accB += ok ? mB : zz;
    }
  }

  float inv = 1.f / fmaxf((float)deg, 1.f);
  uint2 sp = S2[nb4];
  f32x2 sA = unpA(sp.x), sB = unpA(sp.y);
  float v0 = fmaf(accA.x, inv, sA.x);
  float v1 = fmaf(accA.y, inv, sA.y);
  float v2 = fmaf(accB.x, inv, sB.x);
  float v3 = fmaf(accB.y, inv, sB.y);
  v0 = v0 > 0.f ? v0 : 0.01f * v0;
  v1 = v1 > 0.f ? v1 : 0.01f * v1;
  v2 = v2 > 0.f ? v2 : 0.01f * v2;
  v3 = v3 > 0.f ? v3 : 0.01f * v3;
  if (FINAL == 0) {
    if (valid) {
      uint2 pw;
      pw.x = (u32)f2b(v0) | ((u32)f2b(v1) << 16);
      pw.y = (u32)f2b(v2) | ((u32)f2b(v3) << 16);
      ((uint2*)Xn)[nb4] = pw;
    }
  } else {
    float4 w4 = ((const float4*)Wout)[fl];
    float v = fmaf(v0, w4.x, fmaf(v1, w4.y, fmaf(v2, w4.z, v3 * w4.w)));
#pragma unroll
    for (int off = 1; off < 16; off <<= 1) v += __shfl_xor(v, off, 64);
    if (valid && fl == 0) out[node] = v + bout[0];
  }
}

extern "C" void kernel_launch(void* const* d_in, const int* in_sizes, int n_in,
                              void* d_out, int out_size, void* d_ws, size_t ws_size,
                              hipStream_t stream) {
  const float* x = (const float*)d_in[0];
  const int* ei = (const int*)d_in[1];
  const float* Wlin1 = (const float*)d_in[2];
  const float* Wfilm1 = (const float*)d_in[3];
  const float* bfilm1 = (const float*)d_in[4];
  const float* Wskip1 = (const float*)d_in[5];
  const float* Wfs1 = (const float*)d_in[6];
  const float* Wlin2 = (const float*)d_in[7];
  const float* Wfilm2 = (const float*)d_in[8];
  const float* bfilm2 = (const float*)d_in[9];
  const float* Wskip2 = (const float*)d_in[10];
  const float* Wfs2 = (const float*)d_in[11];
  const float* Wout = (const float*)d_in[12];
  const float* bout = (const float*)d_in[13];

  int N = in_sizes[0] / 64;
  int E = in_sizes[1] / 2;
  const int* src = ei;
  const int* dst = ei + E;

  int P = (N + NPSZ - 1) >> NPSHIFT;
  int CH = (E + NB - 1) / NB;
  int NSLOT = P << NPSHIFT;
  int PCAP = P * CAP;

  size_t NF = (size_t)N * 64;
  char* p = (char*)d_ws;
  u8* H8 = (u8*)p;
  p += NF * 2;
  u16* BETA = (u16*)p;
  p += NF * 2;
  u16* GAMMA = (u16*)p;
  p += NF * 2;
  u16* S = (u16*)p;
  p += NF * 2;
  u16* X2 = (u16*)p;  // aliased with buck (buck dead before X2 written)
  u32* buck = (u32*)p;
  size_t bsz = (size_t)PCAP * 4, xsz = NF * 2;
  p += (bsz > xsz ? bsz : xsz);
  u16* Wp = (u16*)p;
  p += 12 * 4096 * 2;
  int* begA = (int*)p;
  p += (size_t)NSLOT * 4;
  int* degA = (int*)p;
  p += (size_t)NSLOT * 4;
  int* csr = (int*)p;
  p += (size_t)PCAP * 4;
  int* perm = (int*)p;
  p += (size_t)NSLOT * 4;
  int* gcur = (int*)p;

  int gemm_blocks = (N + 63) / 64;
  int agg_blocks = NSLOT / 16;  // 4 waves/block, 4 nodes/wave

  WPack wp;
  wp.m[0] = {Wskip1, 64, 0};
  wp.m[1] = {Wfs1, 128, 0};
  wp.m[2] = {Wfs1, 128, 64};
  wp.m[3] = {Wlin1, 64, 0};
  wp.m[4] = {Wfilm1, 128, 0};
  wp.m[5] = {Wfilm1, 128, 64};
  wp.m[6] = {Wskip2, 64, 0};
  wp.m[7] = {Wfs2, 128, 0};
  wp.m[8] = {Wfs2, 128, 64};
  wp.m[9] = {Wlin2, 64, 0};
  wp.m[10] = {Wfilm2, 128, 0};
  wp.m[11] = {Wfilm2, 128, 64};

  hipMemsetAsync(gcur, 0, 256 * sizeof(int), stream);
  prep_and_scatter<<<12 + NB, THREADS, 0, stream>>>(wp, Wp, src, dst, gcur, buck, E,
                                                    CH, P);
  build_and_gemm0<<<P + gemm_blocks, THREADS, 0, stream>>>(
      buck, gcur, begA, degA, csr, perm, x, N, Wp, bfilm1, H8, BETA, GAMMA, S, P);
  agg_kernel<0><<<agg_blocks, THREADS, 0, stream>>>(H8, GAMMA, BETA, S, begA, degA, csr,
                                                    perm, X2, nullptr, nullptr, nullptr,
                                                    N, PCAP);
  gemm_l2<<<gemm_blocks, THREADS, 0, stream>>>(X2, N, Wp + 6 * 4096, bfilm2, H8, BETA,
                                               GAMMA, S);
  agg_kernel<1><<<agg_blocks, THREADS, 0, stream>>>(H8, GAMMA, BETA, S, begA, degA, csr,
                                                    perm, nullptr, Wout, bout,
                                                    (float*)d_out, N, PCAP);
}

// Round 23
// 164.116 us; speedup vs baseline: 1.0445x; 1.0445x over previous
//
#include <hip/hip_runtime.h>
#include <cstddef>

// ---------------------------------------------------------------------------
// GraphFiLM: 2x FiLMConv(mean agg) + leaky_relu + linear head.
// Round 22: revert R21's gemm restructure (6-barrier double-buffer regressed:
// barrier overhead > occupancy gain). Restore R20 config = measured best
// (164.4us): two-trio 32KB gemm, NB=512 scatter, fused build+gemm0, fp8 agg.
// ---------------------------------------------------------------------------

#define THREADS 256
#define NB 512
#define NPSHIFT 9
#define NPSZ 512
#define CAP 10240

typedef unsigned short u16;
typedef unsigned char u8;
typedef unsigned int u32;
typedef short bf16x8 __attribute__((ext_vector_type(8)));
typedef float f32x4 __attribute__((ext_vector_type(4)));
typedef float f32x2 __attribute__((ext_vector_type(2)));

__device__ __forceinline__ u16 f2b(float f) {
  u32 u = __float_as_uint(f);
  u32 r = (u + 0x7FFFu + ((u >> 16) & 1u)) >> 16;
  return (u16)r;
}
__device__ __forceinline__ float b2f(u16 u) {
  return __uint_as_float(((u32)u) << 16);
}
__device__ __forceinline__ u8 f2fp8(float v) {
  return (u8)(__builtin_amdgcn_cvt_pk_fp8_f32(v, v, 0, false) & 0xFF);
}

// ---------------- weight prep + two-pass bucket scatter (merged) ----------
struct WSrc {
  const float* p;
  int ld;
  int off;
};
struct WPack {
  WSrc m[12];
};

__global__ __launch_bounds__(THREADS) void prep_and_scatter(
    WPack wp, u16* __restrict__ Wp, const int* __restrict__ src,
    const int* __restrict__ dst, int* __restrict__ gcur, u32* __restrict__ buck,
    int E, int CH, int P) {
  int b = blockIdx.x, t = threadIdx.x;
  if (b < 12) {
    WSrc ws = wp.m[b];
    u16* dstp = Wp + b * 4096;
#pragma unroll
    for (int i = 0; i < 16; ++i) {
      int e = t + 256 * i;
      int n = e >> 6, k = e & 63;
      float v = ws.p[(size_t)k * ws.ld + ws.off + n];
      dstp[e ^ ((n & 7) << 3)] = f2b(v);
    }
    return;
  }
  __shared__ int h[256];
  __shared__ int cur[256];
  int hb = b - 12;
  h[t] = 0;
  __syncthreads();
  int lo = hb * CH;
  int hi = min(lo + CH, E);
  if (lo >= E) return;
  // pass A: LDS histogram of partitions
  for (int i = lo + t; i < hi; i += THREADS) atomicAdd(&h[dst[i] >> NPSHIFT], 1);
  __syncthreads();
  // reserve global range per partition (one atomic per (block, partition))
  if (t < P) {
    int base = h[t] ? atomicAdd(&gcur[t], h[t]) : 0;
    cur[t] = t * CAP + base;
  }
  __syncthreads();
  // pass B: scatter packed entries (chunk's dst re-read is L1-resident)
  for (int i = lo + t; i < hi; i += THREADS) {
    int d = dst[i];
    int pos = atomicAdd(&cur[d >> NPSHIFT], 1);
    buck[pos] = (u32)src[i] | ((u32)(d & (NPSZ - 1)) << 17);
  }
}

// ---------------- gemm body: two-trio staged (32KB LDS) ----------
// trio 0 (mats 0..2): skip -> S (bf16); trio 1 (mats 3..5): film -> H(fp8),
// BETA, GAMMA.
template <int INBF16>
__device__ __forceinline__ void gemm_body(
    u16* XT, u16* WT, int row0, const void* __restrict__ Xv, int N,
    const u16* __restrict__ WpL, const float* __restrict__ bfilm,
    u8* __restrict__ H8, u16* __restrict__ BETA, u16* __restrict__ GAMMA,
    u16* __restrict__ S) {
  int t = threadIdx.x;
  {
    int row = t >> 2, kq = (t & 3) * 16;
    int gr = row0 + row;
    uint4 w0 = {0, 0, 0, 0}, w1 = {0, 0, 0, 0};
    if (gr < N) {
      if (INBF16) {
        const uint4* xp = (const uint4*)((const u16*)Xv + (size_t)gr * 64 + kq);
        w0 = xp[0];
        w1 = xp[1];
      } else {
        const float* xp = (const float*)Xv + (size_t)gr * 64 + kq;
        float4 f0 = ((const float4*)xp)[0];
        float4 f1 = ((const float4*)xp)[1];
        float4 f2 = ((const float4*)xp)[2];
        float4 f3 = ((const float4*)xp)[3];
        w0.x = f2b(f0.x) | ((u32)f2b(f0.y) << 16);
        w0.y = f2b(f0.z) | ((u32)f2b(f0.w) << 16);
        w0.z = f2b(f1.x) | ((u32)f2b(f1.y) << 16);
        w0.w = f2b(f1.z) | ((u32)f2b(f1.w) << 16);
        w1.x = f2b(f2.x) | ((u32)f2b(f2.y) << 16);
        w1.y = f2b(f2.z) | ((u32)f2b(f2.w) << 16);
        w1.z = f2b(f3.x) | ((u32)f2b(f3.y) << 16);
        w1.w = f2b(f3.z) | ((u32)f2b(f3.w) << 16);
      }
    }
    int e = row * 64 + kq;
    int s = (row & 7) << 3;
    *(uint4*)&XT[e ^ s] = w0;
    *(uint4*)&XT[(e + 8) ^ s] = w1;
  }
  // stage W trio 0 (mats 0..2: 1536 uint4 = 24KB)
  {
    const uint4* wsrc = (const uint4*)WpL;
    uint4* wdst = (uint4*)WT;
    for (int i = t; i < 1536; i += THREADS) wdst[i] = wsrc[i];
  }
  __syncthreads();

  int lane = t & 63, wid = t >> 6;
  int arow = wid * 16 + (lane & 15);
  int kb = (lane >> 4) << 3;
  int as = (arow & 7) << 3;
  bf16x8 A0 = *(const bf16x8*)&XT[(arow * 64 + kb) ^ as];
  bf16x8 A1 = *(const bf16x8*)&XT[(arow * 64 + 32 + kb) ^ as];

  auto bfrag = [&](int mat, int ct, int kk) -> bf16x8 {
    int n = ct * 16 + (lane & 15);
    int e = (n * 64 + kk * 32 + kb) ^ ((n & 7) << 3);
    return *(const bf16x8*)&WT[mat * 4096 + e];
  };

  const f32x4 z = {0.f, 0.f, 0.f, 0.f};
  int rbase = wid * 16 + ((lane >> 4) << 2);
  int cbase = lane & 15;

  f32x4 a0[4], a1[4], a2[4];
#pragma unroll
  for (int ct = 0; ct < 4; ++ct) {
    a0[ct] = z;
    a1[ct] = z;
    a2[ct] = z;
  }
#pragma unroll
  for (int ct = 0; ct < 4; ++ct) {
    a0[ct] = __builtin_amdgcn_mfma_f32_16x16x32_bf16(A0, bfrag(0, ct, 0), a0[ct], 0, 0, 0);
    a0[ct] = __builtin_amdgcn_mfma_f32_16x16x32_bf16(A1, bfrag(0, ct, 1), a0[ct], 0, 0, 0);
    a1[ct] = __builtin_amdgcn_mfma_f32_16x16x32_bf16(A0, bfrag(1, ct, 0), a1[ct], 0, 0, 0);
    a1[ct] = __builtin_amdgcn_mfma_f32_16x16x32_bf16(A1, bfrag(1, ct, 1), a1[ct], 0, 0, 0);
    a2[ct] = __builtin_amdgcn_mfma_f32_16x16x32_bf16(A0, bfrag(2, ct, 0), a2[ct], 0, 0, 0);
    a2[ct] = __builtin_amdgcn_mfma_f32_16x16x32_bf16(A1, bfrag(2, ct, 1), a2[ct], 0, 0, 0);
  }
  __syncthreads();  // all WT(trio0) reads complete
  // stage W trio 1 in-place; overlap with S epilogue below
  {
    const uint4* wsrc = (const uint4*)WpL;
    uint4* wdst = (uint4*)WT;
    for (int i = t; i < 1536; i += THREADS) wdst[i] = wsrc[1536 + i];
  }
#pragma unroll
  for (int ct = 0; ct < 4; ++ct) {
    int c = ct * 16 + cbase;
#pragma unroll
    for (int r = 0; r < 4; ++r) {
      int gr = row0 + rbase + r;
      if (gr < N) {
        float v = fmaxf(fmaf(a2[ct][r], a0[ct][r], a1[ct][r]), 0.f);
        S[(size_t)gr * 64 + c] = f2b(v);
      }
    }
  }
  __syncthreads();  // WT(trio1) staged

#pragma unroll
  for (int ct = 0; ct < 4; ++ct) {
    a0[ct] = z;
    a1[ct] = z;
    a2[ct] = z;
  }
#pragma unroll
  for (int ct = 0; ct < 4; ++ct) {
    a0[ct] = __builtin_amdgcn_mfma_f32_16x16x32_bf16(A0, bfrag(0, ct, 0), a0[ct], 0, 0, 0);
    a0[ct] = __builtin_amdgcn_mfma_f32_16x16x32_bf16(A1, bfrag(0, ct, 1), a0[ct], 0, 0, 0);
    a1[ct] = __builtin_amdgcn_mfma_f32_16x16x32_bf16(A0, bfrag(1, ct, 0), a1[ct], 0, 0, 0);
    a1[ct] = __builtin_amdgcn_mfma_f32_16x16x32_bf16(A1, bfrag(1, ct, 1), a1[ct], 0, 0, 0);
    a2[ct] = __builtin_amdgcn_mfma_f32_16x16x32_bf16(A0, bfrag(2, ct, 0), a2[ct], 0, 0, 0);
    a2[ct] = __builtin_amdgcn_mfma_f32_16x16x32_bf16(A1, bfrag(2, ct, 1), a2[ct], 0, 0, 0);
  }
#pragma unroll
  for (int ct = 0; ct < 4; ++ct) {
    int c = ct * 16 + cbase;
    float bb = bfilm[c];
    float bg = bfilm[64 + c];
#pragma unroll
    for (int r = 0; r < 4; ++r) {
      int gr = row0 + rbase + r;
      if (gr < N) {
        size_t o = (size_t)gr * 64 + c;
        H8[o] = f2fp8(a0[ct][r]);
        BETA[o] = f2b(a1[ct][r] + bb);
        GAMMA[o] = f2b(a2[ct][r] + bg);
      }
    }
  }
}

// ---------------- csr body ----------------
__device__ __forceinline__ void csr_body(
    char* smem, int p, const u32* __restrict__ buck, const int* __restrict__ gcur,
    int* __restrict__ begA, int* __restrict__ degA, int* __restrict__ csr,
    int* __restrict__ perm, int N, int P) {
  int* hA = (int*)smem;
  int* hB = hA + NPSZ;
  int* cur = hB + NPSZ;
  int* h64 = cur + NPSZ;
  int* c64 = h64 + 64;
  int t = threadIdx.x;
  int cnt = gcur[p];
  int pbase = p * CAP;
  hA[t] = 0;
  hA[t + 256] = 0;
  __syncthreads();
  for (int i = t; i < cnt; i += THREADS) atomicAdd(&hA[buck[pbase + i] >> 17], 1);
  __syncthreads();
  int deg0 = hA[t], deg1 = hA[t + 256];
  int* s = hA;
  int* d2 = hB;
  for (int off = 1; off < NPSZ; off <<= 1) {
#pragma unroll
    for (int r = 0; r < 2; ++r) {
      int idx = t + r * 256;
      int v = s[idx];
      if (idx >= off) v += s[idx - off];
      d2[idx] = v;
    }
    __syncthreads();
    int* tmp = s;
    s = d2;
    d2 = tmp;
  }
#pragma unroll
  for (int r = 0; r < 2; ++r) {
    int idx = t + r * 256;
    int excl = idx ? s[idx - 1] : 0;
    cur[idx] = excl;
    int node = (p << NPSHIFT) + idx;
    if (node < N) {
      begA[node] = pbase + excl;
      degA[node] = s[idx] - excl;
    }
  }
  __syncthreads();
  for (int i = t; i < cnt; i += THREADS) {
    u32 w = buck[pbase + i];
    int pos = atomicAdd(&cur[w >> 17], 1);
    csr[pbase + pos] = (int)(w & 0x1FFFFu);
  }
  {
    int padend = min(cnt + 160, CAP);
    for (int i = cnt + t; i < padend; i += THREADS) csr[pbase + i] = 0;
  }
  __syncthreads();
  if (t < 64) h64[t] = 0;
  __syncthreads();
  int b0 = min(deg0, 63), b1 = min(deg1, 63);
  atomicAdd(&h64[b0], 1);
  atomicAdd(&h64[b1], 1);
  __syncthreads();
  if (t == 0) {
    int run = 0;
    for (int i = 0; i < 64; ++i) {
      int v = h64[i];
      c64[i] = run;
      run += v;
    }
  }
  __syncthreads();
  int base_out = p << NPSHIFT;
  int pos0 = atomicAdd(&c64[b0], 1);
  perm[base_out + pos0] = base_out + t;
  int pos1 = atomicAdd(&c64[b1], 1);
  perm[base_out + pos1] = base_out + t + 256;
}

// ---------------- fused: build_csr (blocks 0..P-1) + gemm layer-1 ----------
__global__ __launch_bounds__(THREADS) void build_and_gemm0(
    const u32* __restrict__ buck, const int* __restrict__ gcur,
    int* __restrict__ begA, int* __restrict__ degA, int* __restrict__ csr,
    int* __restrict__ perm, const float* __restrict__ X, int N,
    const u16* __restrict__ Wp, const float* __restrict__ bfilm,
    u8* __restrict__ H8, u16* __restrict__ BETA, u16* __restrict__ GAMMA,
    u16* __restrict__ S, int P) {
  __shared__ __align__(16) char smem[32768];  // gemm: 8K XT + 24K WT; csr: 6.5K
  if ((int)blockIdx.x < P) {
    csr_body(smem, blockIdx.x, buck, gcur, begA, degA, csr, perm, N, P);
  } else {
    u16* XT = (u16*)smem;
    u16* WT = XT + 4096;
    int row0 = ((int)blockIdx.x - P) * 64;
    gemm_body<0>(XT, WT, row0, X, N, Wp, bfilm, H8, BETA, GAMMA, S);
  }
}

// ---------------- standalone gemm (layer 2, bf16 input) ----------
__global__ __launch_bounds__(THREADS) void gemm_l2(
    const u16* __restrict__ X2, int N, const u16* __restrict__ WpL,
    const float* __restrict__ bfilm, u8* __restrict__ H8, u16* __restrict__ BETA,
    u16* __restrict__ GAMMA, u16* __restrict__ S) {
  __shared__ __align__(16) char smem[32768];
  u16* XT = (u16*)smem;
  u16* WT = XT + 4096;
  gemm_body<1>(XT, WT, blockIdx.x * 64, X2, N, WpL, bfilm, H8, BETA, GAMMA, S);
}

// ---------------- dst-centric aggregation v9 (fp8 H gather) ----------------
template <int FINAL>
__global__ __launch_bounds__(THREADS) void agg_kernel(
    const u8* __restrict__ H8, const u16* __restrict__ GAMMA,
    const u16* __restrict__ BETA, const u16* __restrict__ S,
    const int* __restrict__ begA, const int* __restrict__ degA,
    const int* __restrict__ csr, const int* __restrict__ perm,
    u16* __restrict__ Xn, const float* __restrict__ Wout,
    const float* __restrict__ bout, float* __restrict__ out, int N, int PCAP) {
  int wid = blockIdx.x * 4 + (threadIdx.x >> 6);
  int lane = threadIdx.x & 63;
  int q = lane >> 4;
  int fl = lane & 15;
  int node = perm[wid * 4 + q];
  bool valid = node < N;
  int nd = valid ? node : N - 1;
  int beg = begA[nd];
  int deg = valid ? degA[nd] : 0;
  int m = deg;
  m = max(m, __shfl_xor(m, 16, 64));
  m = max(m, __shfl_xor(m, 32, 64));

  size_t nb4 = (size_t)nd * 16 + fl;
  const uint2* G2 = (const uint2*)GAMMA;
  const uint2* B2 = (const uint2*)BETA;
  const u32* H1 = (const u32*)H8;
  const uint2* S2 = (const uint2*)S;
  uint2 gp = G2[nb4];
  uint2 bp = B2[nb4];

  auto unpA = [](u32 h) -> f32x2 {
    f32x2 r = {__uint_as_float(h << 16), __uint_as_float(h & 0xFFFF0000u)};
    return r;
  };
  f32x2 gA = unpA(gp.x), gB = unpA(gp.y);
  f32x2 bA = unpA(bp.x), bB = unpA(bp.y);
  const f32x2 zz = {0.f, 0.f};
  f32x2 accA = zz, accB = zz;
  int qb = q * 16;

  for (int c = 0; c < m; c += 16) {        // uniform
    int li = beg + c + fl;
    int idxv = csr[min(li, PCAP - 1)];     // clamped; slack padded with 0
    int nin = min(16, m - c);              // uniform
#pragma unroll 4
    for (int u = 0; u < 16; u += 4) {
      if (u >= nin) break;                 // uniform condition
      int s0 = __shfl(idxv, qb + u + 0, 64);
      int s1 = __shfl(idxv, qb + u + 1, 64);
      int s2 = __shfl(idxv, qb + u + 2, 64);
      int s3 = __shfl(idxv, qb + u + 3, 64);
      u32 h0 = H1[(size_t)s0 * 16 + fl];
      u32 h1 = H1[(size_t)s1 * 16 + fl];
      u32 h2 = H1[(size_t)s2 * 16 + fl];
      u32 h3 = H1[(size_t)s3 * 16 + fl];
      int e0 = c + u;
      f32x2 lo, hi, mA, mB;
      bool ok;
      lo = __builtin_amdgcn_cvt_pk_f32_fp8((int)h0, false);
      hi = __builtin_amdgcn_cvt_pk_f32_fp8((int)h0, true);
      mA = __builtin_elementwise_max(__builtin_elementwise_fma(gA, lo, bA), zz);
      mB = __builtin_elementwise_max(__builtin_elementwise_fma(gB, hi, bB), zz);
      ok = e0 + 0 < deg;
      accA += ok ? mA : zz;
      accB += ok ? mB : zz;
      lo = __builtin_amdgcn_cvt_pk_f32_fp8((int)h1, false);
      hi = __builtin_amdgcn_cvt_pk_f32_fp8((int)h1, true);
      mA = __builtin_elementwise_max(__builtin_elementwise_fma(gA, lo, bA), zz);
      mB = __builtin_elementwise_max(__builtin_elementwise_fma(gB, hi, bB), zz);
      ok = e0 + 1 < deg;
      accA += ok ? mA : zz;
      accB += ok ? mB : zz;
      lo = __builtin_amdgcn_cvt_pk_f32_fp8((int)h2, false);
      hi = __builtin_amdgcn_cvt_pk_f32_fp8((int)h2, true);
      mA = __builtin_elementwise_max(__builtin_elementwise_fma(gA, lo, bA), zz);
      mB = __builtin_elementwise_max(__builtin_elementwise_fma(gB, hi, bB), zz);
      ok = e0 + 2 < deg;
      accA += ok ? mA : zz;
      accB += ok ? mB : zz;
      lo = __builtin_amdgcn_cvt_pk_f32_fp8((int)h3, false);
      hi = __builtin_amdgcn_cvt_pk_f32_fp8((int)h3, true);
      mA = __builtin_elementwise_max(__builtin_elementwise_fma(gA, lo, bA), zz);
      mB = __builtin_elementwise_max(__builtin_elementwise_fma(gB, hi, bB), zz);
      ok = e0 + 3 < deg;
      accA += ok ? mA : zz;
      accB += ok ? mB : zz;
    }
  }

  float inv = 1.f / fmaxf((float)deg, 1.f);
  uint2 sp = S2[nb4];
  f32x2 sA = unpA(sp.x), sB = unpA(sp.y);
  float v0 = fmaf(accA.x, inv, sA.x);
  float v1 = fmaf(accA.y, inv, sA.y);
  float v2 = fmaf(accB.x, inv, sB.x);
  float v3 = fmaf(accB.y, inv, sB.y);
  v0 = v0 > 0.f ? v0 : 0.01f * v0;
  v1 = v1 > 0.f ? v1 : 0.01f * v1;
  v2 = v2 > 0.f ? v2 : 0.01f * v2;
  v3 = v3 > 0.f ? v3 : 0.01f * v3;
  if (FINAL == 0) {
    if (valid) {
      uint2 pw;
      pw.x = (u32)f2b(v0) | ((u32)f2b(v1) << 16);
      pw.y = (u32)f2b(v2) | ((u32)f2b(v3) << 16);
      ((uint2*)Xn)[nb4] = pw;
    }
  } else {
    float4 w4 = ((const float4*)Wout)[fl];
    float v = fmaf(v0, w4.x, fmaf(v1, w4.y, fmaf(v2, w4.z, v3 * w4.w)));
#pragma unroll
    for (int off = 1; off < 16; off <<= 1) v += __shfl_xor(v, off, 64);
    if (valid && fl == 0) out[node] = v + bout[0];
  }
}

extern "C" void kernel_launch(void* const* d_in, const int* in_sizes, int n_in,
                              void* d_out, int out_size, void* d_ws, size_t ws_size,
                              hipStream_t stream) {
  const float* x = (const float*)d_in[0];
  const int* ei = (const int*)d_in[1];
  const float* Wlin1 = (const float*)d_in[2];
  const float* Wfilm1 = (const float*)d_in[3];
  const float* bfilm1 = (const float*)d_in[4];
  const float* Wskip1 = (const float*)d_in[5];
  const float* Wfs1 = (const float*)d_in[6];
  const float* Wlin2 = (const float*)d_in[7];
  const float* Wfilm2 = (const float*)d_in[8];
  const float* bfilm2 = (const float*)d_in[9];
  const float* Wskip2 = (const float*)d_in[10];
  const float* Wfs2 = (const float*)d_in[11];
  const float* Wout = (const float*)d_in[12];
  const float* bout = (const float*)d_in[13];

  int N = in_sizes[0] / 64;
  int E = in_sizes[1] / 2;
  const int* src = ei;
  const int* dst = ei + E;

  int P = (N + NPSZ - 1) >> NPSHIFT;
  int CH = (E + NB - 1) / NB;
  int NSLOT = P << NPSHIFT;
  int PCAP = P * CAP;

  size_t NF = (size_t)N * 64;
  char* p = (char*)d_ws;
  u8* H8 = (u8*)p;
  p += NF * 2;
  u16* BETA = (u16*)p;
  p += NF * 2;
  u16* GAMMA = (u16*)p;
  p += NF * 2;
  u16* S = (u16*)p;
  p += NF * 2;
  u16* X2 = (u16*)p;  // aliased with buck (buck dead before X2 written)
  u32* buck = (u32*)p;
  size_t bsz = (size_t)PCAP * 4, xsz = NF * 2;
  p += (bsz > xsz ? bsz : xsz);
  u16* Wp = (u16*)p;
  p += 12 * 4096 * 2;
  int* begA = (int*)p;
  p += (size_t)NSLOT * 4;
  int* degA = (int*)p;
  p += (size_t)NSLOT * 4;
  int* csr = (int*)p;
  p += (size_t)PCAP * 4;
  int* perm = (int*)p;
  p += (size_t)NSLOT * 4;
  int* gcur = (int*)p;

  int gemm_blocks = (N + 63) / 64;
  int agg_blocks = NSLOT / 16;  // 4 waves/block, 4 nodes/wave

  WPack wp;
  wp.m[0] = {Wskip1, 64, 0};
  wp.m[1] = {Wfs1, 128, 0};
  wp.m[2] = {Wfs1, 128, 64};
  wp.m[3] = {Wlin1, 64, 0};
  wp.m[4] = {Wfilm1, 128, 0};
  wp.m[5] = {Wfilm1, 128, 64};
  wp.m[6] = {Wskip2, 64, 0};
  wp.m[7] = {Wfs2, 128, 0};
  wp.m[8] = {Wfs2, 128, 64};
  wp.m[9] = {Wlin2, 64, 0};
  wp.m[10] = {Wfilm2, 128, 0};
  wp.m[11] = {Wfilm2, 128, 64};

  hipMemsetAsync(gcur, 0, 256 * sizeof(int), stream);
  prep_and_scatter<<<12 + NB, THREADS, 0, stream>>>(wp, Wp, src, dst, gcur, buck, E,
                                                    CH, P);
  build_and_gemm0<<<P + gemm_blocks, THREADS, 0, stream>>>(
      buck, gcur, begA, degA, csr, perm, x, N, Wp, bfilm1, H8, BETA, GAMMA, S, P);
  agg_kernel<0><<<agg_blocks, THREADS, 0, stream>>>(H8, GAMMA, BETA, S, begA, degA, csr,
                                                    perm, X2, nullptr, nullptr, nullptr,
                                                    N, PCAP);
  gemm_l2<<<gemm_blocks, THREADS, 0, stream>>>(X2, N, Wp + 6 * 4096, bfilm2, H8, BETA,
                                               GAMMA, S);
  agg_kernel<1><<<agg_blocks, THREADS, 0, stream>>>(H8, GAMMA, BETA, S, begA, degA, csr,
                                                    perm, nullptr, Wout, bout,
                                                    (float*)d_out, N, PCAP);
}